// Round 13
// baseline (342.717 us; speedup 1.0000x reference)
//
#include <hip/hip_runtime.h>
#include <hip/hip_bf16.h>

#define HW 9216      // 96*96

typedef unsigned short ushort;
typedef unsigned int   uint;
typedef __attribute__((ext_vector_type(4))) float f32x4;
typedef __attribute__((ext_vector_type(2))) uint  u32x2;
typedef __attribute__((ext_vector_type(4))) uint  u32x4;
typedef __attribute__((ext_vector_type(4))) int   i32x4;
typedef __attribute__((ext_vector_type(8))) short s16x8;
typedef __attribute__((ext_vector_type(8))) _Float16 f16x8;

// ---------------- module-global intermediates (BSS) ----------------
__device__ float  g_o1[4*32*HW];                 // conv1 out (bias+relu) fp32
__device__ float  g_q [2*4*26*HW];               // conv2 split-K=2 partials (bias in kg0)
__device__ __align__(16) _Float16 g_hh[4*(size_t)HW*96]; // hp transposed fp16: [b][px][96ch] (gather table)
__device__ __align__(16) ushort g_chi[4*(size_t)HW*128]; // concat [x;hp] transposed, bf16 HI, ch-pad to 128
__device__ __align__(16) ushort g_clo[4*(size_t)HW*128]; // bf16 LO residual
__device__ __align__(16) ushort g_w1b[32*4*2048];        // conv1 W: [(tap*4+cb)][hl][nt][16oc][32k] bf16; taps 25..31 BSS-zero
__device__ __align__(16) ushort g_b[18*39*512];  // weights bf16, layout [nt][kb][lane=q*16+nl][8] (conflict-free)
__device__ __align__(16) float  g_urv[2304*288*16]; // GEMM out, tile-major [pt][n][16px]

__device__ __forceinline__ ushort f2b(float f){  // fp32 -> bf16 bits, RNE
  uint x = __float_as_uint(f);
  return (ushort)((x + 0x7FFFu + ((x >> 16) & 1u)) >> 16);
}
__device__ __forceinline__ float b2f(ushort h){
  return __uint_as_float(((uint)h) << 16);
}

// ---------------- K0: pack 1x1 weights into B-fragment layout
// K-ordering PERMUTED: k' = l*96 + c  (weight flat index = c*13 + l)
// Within (nt,kb): lane-linear fragments: ushort idx = ((kk>>3)*16 + nl)*8 + (kk&7)
__global__ void pack_b_k(const float* __restrict__ uww, const float* __restrict__ rww,
                         const float* __restrict__ vww){
  int i = blockIdx.x*256 + threadIdx.x;
  if (i >= 3*96*1248) return;
  int gate = i / (96*1248); int rem = i % (96*1248);
  int oc = rem / 1248;      int kp = rem % 1248;   // k' position
  int l = kp / 96, c = kp % 96;
  const float* src = (gate == 0) ? uww : ((gate == 1) ? rww : vww);
  float v = src[oc*1248 + c*13 + l];
  int n  = gate*96 + oc;
  int nt = n >> 4, nl = n & 15;
  int kb = kp >> 5, kk = kp & 31;
  g_b[(nt*39 + kb)*512 + ((kk >> 3)*16 + nl)*8 + (kk & 7)] = f2b(v);
}

// ---------------- K0a: pack conv1 weights -> bf16 hi/lo MFMA B-fragments
// sw1 layout: (32 oc, 104 ci, 5, 5). Pad ci to 128 with zeros (makes g_c* pad inert).
__global__ void pack_w1b_k(const float* __restrict__ w1){
  int i = blockIdx.x*256 + threadIdx.x;
  if (i >= 25*4*1024) return;
  int tap = i >> 12;
  int cb  = (i >> 10) & 3;
  int oc  = (i >> 5) & 31;
  int kk  = i & 31;
  int ci  = cb*32 + kk;
  float w = (ci < 104) ? w1[oc*2600 + ci*25 + tap] : 0.f;
  ushort h = f2b(w);
  float rem = w - b2f(h);
  int base = ((tap*4 + cb) << 11) + (oc >> 4)*512 + (oc & 15)*32 + kk;
  g_w1b[base]        = h;         // hi
  g_w1b[base + 1024] = f2b(rem);  // lo
}

// ---------------- K0b: transpose hp (B,C,HW) -> g_hh (fp16) + g_chi/g_clo (bf16, ch 8..103)
//                 blockIdx.y==3 handles x -> g_chi/g_clo ch 0..7
__global__ __launch_bounds__(256) void transpose_k(const float* __restrict__ hp,
                                                   const float* __restrict__ x){
  __shared__ float tile[32][33];
  int s0 = blockIdx.x*32;          // spatial tile
  int b  = blockIdx.z;
  int t  = threadIdx.x;
  if (blockIdx.y < 3){
    int c0 = blockIdx.y*32;        // channel tile (96 = 3*32)
    for (int i = t; i < 32*32; i += 256){
      int c = i >> 5, s = i & 31;
      tile[c][s] = hp[((size_t)(b*96 + c0 + c))*HW + s0 + s];
    }
    __syncthreads();
    for (int i = t; i < 32*32; i += 256){
      int s = i >> 5, c = i & 31;
      float v = tile[c][s];
      size_t px = (size_t)b*HW + s0 + s;
      g_hh[px*96 + c0 + c] = (_Float16)v;
      ushort h = f2b(v);
      g_chi[px*128 + 8 + c0 + c] = h;
      g_clo[px*128 + 8 + c0 + c] = f2b(v - b2f(h));
    }
  } else {
    for (int i = t; i < 8*32; i += 256){
      int c = i >> 5, s = i & 31;
      tile[c][s] = x[((size_t)(b*8 + c))*HW + s0 + s];
    }
    __syncthreads();
    for (int i = t; i < 32*8; i += 256){
      int s = i >> 3, c = i & 7;
      float v = tile[c][s];
      size_t px = (size_t)b*HW + s0 + s;
      ushort h = f2b(v);
      g_chi[px*128 + c] = h;
      g_clo[px*128 + c] = f2b(v - b2f(h));
    }
  }
}

// ---------------- K1: conv1 5x5 pad2 (104ch->32ch) via MFMA, 3-term bf16 split
// 8 waves/block (512 thr), split-K over taps: wave w owns taps 4w..4w+3
// (25 real taps padded to 32; pads have BSS-zero weights, clamped A-address).
__global__ __launch_bounds__(512) void conv1_mfma_k(const float* __restrict__ b1){
  __shared__ __align__(16) ushort sh[2*160*128];   // 80 KB; reused as 64 KB reduce buf
  int t = threadIdx.x;
  int w = t >> 6, lane = t & 63;
  int nl = lane & 15, q = lane >> 4;
  int rt = blockIdx.x / 6, ct = blockIdx.x % 6;    // 24 row-tiles x 6 col-tiles
  int b  = blockIdx.z;
  int r0 = rt*4, c0 = ct*16;
  const size_t pbase = (size_t)b*HW;

  // ---- cooperative stage: 5120 16B-chunks, 10 per thread, one exposure
  #pragma unroll
  for (int i = 0; i < 10; i++){
    int idx = i*512 + t;
    int half = (i >= 5) ? 1 : 0;                   // 0: hi (g_chi), 1: lo (g_clo)
    int rem = idx - half*2560;
    int px = rem >> 4, ci = rem & 15;
    int cs = ci ^ (px & 15);                       // source-chunk swizzle
    int r = px / 20, c = px - r*20;
    int gr = r0 + r - 2, gc = c0 + c - 2;
    f32x4 v = (f32x4){0.f,0.f,0.f,0.f};
    if ((unsigned)gr < 96u && (unsigned)gc < 96u){
      const ushort* src = half ? g_clo : g_chi;
      v = *(const f32x4*)(src + ((pbase + (size_t)(gr*96 + gc)) << 7) + cs*8);
    }
    *(f32x4*)((char*)sh + (size_t)idx*16) = v;     // linear LDS write: free
  }
  __syncthreads();

  // per-wave tap set: tp = 4w + i, i = 0..3 (static unroll; dead taps have zero B)
  int kxA[4], kyA[4], tpA[4];
  #pragma unroll
  for (int i = 0; i < 4; i++){
    int tp  = 4*w + i;
    int tpc = (tp > 24) ? 24 : tp;                 // clamp A-address; B is zero there
    kyA[i] = tpc / 5;
    kxA[i] = tpc - kyA[i]*5;
    tpA[i] = tp;
  }
  int foff = nl*32 + q*8;                          // B-frag lane offset (shorts)

  f32x4 acc[4][2];
  #pragma unroll
  for (int mr = 0; mr < 4; mr++){
    acc[mr][0] = (f32x4){0.f,0.f,0.f,0.f};
    acc[mr][1] = (f32x4){0.f,0.f,0.f,0.f};
  }

  for (int cb = 0; cb < 4; cb++){
    const ushort* bpc = g_w1b + ((size_t)cb << 11);
    s16x8 bq[3][4];
#define LOADB(slot, i) { const ushort* bp = bpc + ((size_t)tpA[i] << 13); \
    bq[slot][0] = *(const s16x8*)(bp + foff); \
    bq[slot][1] = *(const s16x8*)(bp + 512 + foff); \
    bq[slot][2] = *(const s16x8*)(bp + 1024 + foff); \
    bq[slot][3] = *(const s16x8*)(bp + 1536 + foff); }
    LOADB(0, 0); LOADB(1, 1);

    #pragma unroll
    for (int i = 0; i < 4; i++){
      if (i < 2) LOADB((i + 2) % 3, i + 2);        // static rotation (i is literal)
      int ky = kyA[i], kx = kxA[i];
      int chq = cb*4 + q;
      s16x8 ah[4], al[4];
      #pragma unroll
      for (int mr = 0; mr < 4; mr++){
        int px  = (mr + ky)*20 + kx + nl;
        int off = px*256 + (((chq ^ (px & 15))) << 4);
        ah[mr] = *(const s16x8*)((const char*)sh + off);
        al[mr] = *(const s16x8*)((const char*)sh + 40960 + off);
      }
      const int cur = i % 3;
      #pragma unroll
      for (int mr = 0; mr < 4; mr++){
        acc[mr][0] = __builtin_amdgcn_mfma_f32_16x16x32_bf16(ah[mr], bq[cur][0], acc[mr][0], 0,0,0);
        acc[mr][1] = __builtin_amdgcn_mfma_f32_16x16x32_bf16(ah[mr], bq[cur][1], acc[mr][1], 0,0,0);
      }
      #pragma unroll
      for (int mr = 0; mr < 4; mr++){
        acc[mr][0] = __builtin_amdgcn_mfma_f32_16x16x32_bf16(al[mr], bq[cur][0], acc[mr][0], 0,0,0);
        acc[mr][1] = __builtin_amdgcn_mfma_f32_16x16x32_bf16(al[mr], bq[cur][1], acc[mr][1], 0,0,0);
      }
      #pragma unroll
      for (int mr = 0; mr < 4; mr++){
        acc[mr][0] = __builtin_amdgcn_mfma_f32_16x16x32_bf16(ah[mr], bq[cur][2], acc[mr][0], 0,0,0);
        acc[mr][1] = __builtin_amdgcn_mfma_f32_16x16x32_bf16(ah[mr], bq[cur][3], acc[mr][1], 0,0,0);
      }
    }
#undef LOADB
  }

  // ---- cross-wave reduction through LDS (reuse halo buffer; 64 KB of 80)
  __syncthreads();
  float* red = (float*)sh;                         // slot(mr,nt,w): 1 KB each
  #pragma unroll
  for (int mr = 0; mr < 4; mr++)
    #pragma unroll
    for (int nt = 0; nt < 2; nt++)
      *(f32x4*)&red[(((mr*2 + nt)*8 + w) << 8) + lane*4] = acc[mr][nt];
  __syncthreads();

  int mr = w >> 1, nt = w & 1;                     // wave w finalizes (mr, nt)
  {
    f32x4 s = (f32x4){0.f,0.f,0.f,0.f};
    #pragma unroll
    for (int ww = 0; ww < 8; ww++)
      s += *(f32x4*)&red[(((mr*2 + nt)*8 + ww) << 8) + lane*4];
    int oc = nt*16 + nl;
    float bias = b1[oc];
    s.x = fmaxf(s.x + bias, 0.f); s.y = fmaxf(s.y + bias, 0.f);
    s.z = fmaxf(s.z + bias, 0.f); s.w = fmaxf(s.w + bias, 0.f);
    *(f32x4*)(g_o1 + ((size_t)(b*32 + oc))*HW + (size_t)(r0 + mr)*96 + c0 + q*4) = s;
  }
}

// ---------------- K3: conv2 5x5 pad2 (32ch->26ch), split-K=2 (16 ic) x 72 spatial tiles
// 576 blocks (2.25/CU), single stage + single barrier. Tile = 8 rows x 16 cols.
// Thread map: og = t>>5 (4 oc each), pos = t&31: row = pos>>2, 4-col segment.
__global__ __launch_bounds__(256) void conv2_k(const float* __restrict__ wt2,
                                               const float* __restrict__ b2){
  __shared__ __align__(16) float in_sh[16][12][24]; // 18 KB
  __shared__ __align__(16) float w_sh[16][25][32];  // 50 KB
  int tile = blockIdx.x;           // 0..71: 12 row-tiles x 6 col-tiles
  int kg   = blockIdx.y;           // 0..1, owns ic 16*kg..16*kg+15
  int b    = blockIdx.z;
  int row0 = (tile / 6) * 8, col0 = (tile % 6) * 16;
  int t = threadIdx.x;
  int og  = t >> 5;                // 0..7 -> oc og*4..og*4+3
  int pos = t & 31;
  int row = pos >> 2, x0 = (pos & 3)*4;

  float acc[4][4];
  #pragma unroll
  for (int j = 0; j < 4; j++)
    #pragma unroll
    for (int o = 0; o < 4; o++) acc[j][o] = 0.f;

  for (int idx = t; idx < 16*12*24; idx += 256){
    int i = idx / 288, rem = idx % 288;
    int r = rem / 24, c = rem % 24;
    int gr = row0 + r - 2, gc = col0 + c - 2;
    float v = 0.f;
    if ((unsigned)gr < 96u && (unsigned)gc < 96u){
      int ci = kg*16 + i;
      v = g_o1[(b*32 + ci)*HW + gr*96 + gc];
    }
    in_sh[i][r][c] = v;
  }
  for (int idx = t; idx < 16*25*32; idx += 256){
    int i = idx / 800, rem = idx % 800;
    int tap = rem / 32, oc = rem & 31;
    int ci = kg*16 + i;
    w_sh[i][tap][oc] = (oc < 26) ? wt2[oc*800 + ci*25 + tap] : 0.f;
  }
  __syncthreads();

  for (int i = 0; i < 16; i++){
    #pragma unroll
    for (int ky = 0; ky < 5; ky++){
      const float* rp = &in_sh[i][row + ky][x0];
      f32x4 s0 = *(const f32x4*)(rp);
      f32x4 s1 = *(const f32x4*)(rp + 4);
      float seg[8] = {s0.x,s0.y,s0.z,s0.w, s1.x,s1.y,s1.z,s1.w};
      #pragma unroll
      for (int kx = 0; kx < 5; kx++){
        f32x4 wv = *(const f32x4*)&w_sh[i][ky*5 + kx][og*4];
        #pragma unroll
        for (int j = 0; j < 4; j++){
          float a = seg[kx + j];
          acc[j][0] += a*wv.x; acc[j][1] += a*wv.y;
          acc[j][2] += a*wv.z; acc[j][3] += a*wv.w;
        }
      }
    }
  }

  int rg = row0 + row, cg = col0 + x0;
  #pragma unroll
  for (int o = 0; o < 4; o++){
    int slot = og*4 + o;
    if (slot < 26){
      float bias = (kg == 0) ? b2[slot] : 0.f;
      float* d = g_q + (size_t)kg*4*26*HW + ((size_t)(b*26 + slot))*HW + rg*96 + cg;
      #pragma unroll
      for (int j = 0; j < 4; j++) d[j] = acc[j][o] + bias;
    }
  }
}

// ---------------- K5: FUSED sample + MFMA GEMM -> g_urv (tile-major)  [R9 structure]
// XCD-pinned block remap (keeps FETCH low). l=12 plane exactly zero -> 36 bodies.
// fp16 gathers, fp32 weighting, RNE pack. Distance-1 pipeline, raw barriers.
__global__ __launch_bounds__(256) void gemm_k(){
  __shared__ __align__(16) ushort Bsh[18*512];     // 18 KB, [nt][lane][8 ushorts]
  __shared__ __align__(16) float cw4[12][64][4];   // 12 KB: bilinear weights (z-folded)
  __shared__ __align__(16) int   co4[12][64][4];   // 12 KB: corner pixel offsets
  int t = threadIdx.x;
  int w = t >> 6, lane = t & 63;
  int nl = lane & 15, quad = lane >> 4;
  int L   = blockIdx.x;            // 0..575
  int blk = (L & 7)*72 + (L >> 3); // bijective XCD-pinned remap (576 = 8*72)
  int b   = blk / 144;             // 4 pt per block, 144 blocks per batch
  int pbase0 = (blk % 144) * 64;   // first pixel of this block's 64-px strip
  int pt  = blk*4 + w;

  // ---- prologue: weights/offsets for 64 px x 12 l (all 256 threads)
  const int NQ = 4*26*HW;
  for (int idx = t; idx < 768; idx += 256){
    int l = idx >> 6, m = idx & 63;
    int p = pbase0 + m;
    float gx = fmaxf(g_q[(b*26 + l     )*HW + p] + g_q[NQ + (b*26 + l     )*HW + p], 0.f);
    float gy = fmaxf(g_q[(b*26 + 13 + l)*HW + p] + g_q[NQ + (b*26 + 13 + l)*HW + p], 0.f);
    float ix = gx * (96.f/95.f) - 0.5f;
    float iy = gy * (96.f/95.f) - 0.5f;
    float iz = (float)(l+1) * (13.f/12.f) - 0.5f;
    float z0 = floorf(iz);
    float zf = 0.f;
    #pragma unroll
    for (int dz = 0; dz < 2; dz++){
      float zc = z0 + (float)dz;
      float wz = 1.f - fabsf(iz - zc);
      if (zc >= 0.f && zc <= 12.f) zf += wz;
    }
    float x0f = floorf(ix), y0f = floorf(iy);
    #pragma unroll
    for (int dy = 0; dy < 2; dy++){
      float yc = y0f + (float)dy;
      float wy = 1.f - fabsf(iy - yc);
      bool  my = (yc >= 0.f) && (yc <= 95.f);
      int  yci = min(max((int)yc, 0), 95);
      #pragma unroll
      for (int dx = 0; dx < 2; dx++){
        float xc = x0f + (float)dx;
        float wx = 1.f - fabsf(ix - xc);
        bool  mx = (xc >= 0.f) && (xc <= 95.f);
        int  xci = min(max((int)xc, 0), 95);
        cw4[l][m][dy*2+dx] = (mx && my) ? zf*wy*wx : 0.f;
        co4[l][m][dy*2+dx] = yci*96 + xci;
      }
    }
  }

  f32x4 acc[18];
  #pragma unroll
  for (int nt = 0; nt < 18; nt++) acc[nt] = (f32x4){0.f,0.f,0.f,0.f};

  const u32x2* Bg8 = reinterpret_cast<const u32x2*>(g_b);
  const _Float16* hb = g_hh + (size_t)b*HW*96 + quad*8;  // + kb3*32 per iter
  int mloc = w*16 + nl;

  f16x8 gA[4], gB[4];
  f32x4 wA, wB;
  u32x2 sA[9], sB[9];

  // stage kb=0 (independent of cw4) — issued before the publishing barrier
  #pragma unroll
  for (int u = 0; u < 9; u++){
    int idx8 = u*256 + t;
    sA[u] = Bg8[((idx8 >> 7)*39 + 0)*128 + (idx8 & 127)];
  }
  __syncthreads();                 // publish cw4/co4 (one-time full drain, OK)

  // gather kb=0 (l=0, kb3=0) into set A
  {
    wA = *(const f32x4*)cw4[0][mloc];
    i32x4 ov_ = *(const i32x4*)co4[0][mloc];
    gA[0] = *(const f16x8*)(hb + (size_t)ov_.x*96);
    gA[1] = *(const f16x8*)(hb + (size_t)ov_.y*96);
    gA[2] = *(const f16x8*)(hb + (size_t)ov_.z*96);
    gA[3] = *(const f16x8*)(hb + (size_t)ov_.w*96);
  }
  int ln = 0, k3n = 1;             // (l, kb3) of kb+1

#define BODY(KB, GC, WC, GN, WN, SC, SN, PF) { \
  if (PF){ \
    _Pragma("unroll") \
    for (int u = 0; u < 9; u++){ \
      int idx8 = u*256 + t; \
      SN[u] = Bg8[((idx8 >> 7)*39 + (KB) + 1)*128 + (idx8 & 127)]; \
    } \
    WN = *(const f32x4*)cw4[ln][mloc]; \
    i32x4 ov_ = *(const i32x4*)co4[ln][mloc]; \
    const _Float16* hc_ = hb + k3n*32; \
    GN[0] = *(const f16x8*)(hc_ + (size_t)ov_.x*96); \
    GN[1] = *(const f16x8*)(hc_ + (size_t)ov_.y*96); \
    GN[2] = *(const f16x8*)(hc_ + (size_t)ov_.z*96); \
    GN[3] = *(const f16x8*)(hc_ + (size_t)ov_.w*96); \
    k3n++; if (k3n == 3){ k3n = 0; ln++; } \
  } \
  _Pragma("unroll") \
  for (int u = 0; u < 9; u++){ \
    int idx8 = u*256 + t; \
    *(u32x2*)((char*)Bsh + idx8*8) = SC[u]; \
  } \
  float av[8]; \
  _Pragma("unroll") \
  for (int j = 0; j < 8; j++) \
    av[j] = WC.x*(float)GC[0][j] + WC.y*(float)GC[1][j] \
          + WC.z*(float)GC[2][j] + WC.w*(float)GC[3][j]; \
  union { u32x4 u4; s16x8 s8v; } cv_; \
  cv_.u4.x = (uint)f2b(av[0]) | ((uint)f2b(av[1]) << 16); \
  cv_.u4.y = (uint)f2b(av[2]) | ((uint)f2b(av[3]) << 16); \
  cv_.u4.z = (uint)f2b(av[4]) | ((uint)f2b(av[5]) << 16); \
  cv_.u4.w = (uint)f2b(av[6]) | ((uint)f2b(av[7]) << 16); \
  asm volatile("s_waitcnt lgkmcnt(0)" ::: "memory"); \
  __builtin_amdgcn_s_barrier(); \
  asm volatile("" ::: "memory"); \
  _Pragma("unroll") \
  for (int nt = 0; nt < 18; nt++){ \
    s16x8 bf = *(const s16x8*)((const char*)Bsh + nt*1024 + lane*16); \
    acc[nt] = __builtin_amdgcn_mfma_f32_16x16x32_bf16(cv_.s8v, bf, acc[nt], 0, 0, 0); \
  } \
  asm volatile("" ::: "memory"); \
  __builtin_amdgcn_s_barrier(); \
  asm volatile("" ::: "memory"); \
}

  for (int kb = 0; kb < 34; kb += 2){
    BODY(kb,     gA, wA, gB, wB, sA, sB, 1);
    BODY(kb + 1, gB, wB, gA, wA, sB, sA, 1);
  }
  BODY(34, gA, wA, gB, wB, sA, sB, 1);
  BODY(35, gB, wB, gA, wA, sB, sA, 0);
#undef BODY

  float* dst = g_urv + (size_t)pt*4608;          // [pt][n=288][px=16]
  #pragma unroll
  for (int nt = 0; nt < 18; nt++)
    *(f32x4*)&dst[(nt*16 + nl)*16 + quad*4] = acc[nt];
}

// ---------------- K6: fused 3x3 convs on x + gating -> out
__global__ __launch_bounds__(256) void gate_k(const float* __restrict__ x,
                        const float* __restrict__ hp,
                        const float* __restrict__ uw, const float* __restrict__ ub,
                        const float* __restrict__ rw, const float* __restrict__ rb,
                        const float* __restrict__ vw, const float* __restrict__ vb,
                        const float* __restrict__ uwb, const float* __restrict__ rwb,
                        const float* __restrict__ vwb, float* __restrict__ out){
  int p  = blockIdx.x*256 + threadIdx.x;
  int oc = blockIdx.y;
  int b  = blockIdx.z;
  int h = p/96, w = p%96;
  float xU = ub[oc], xR = rb[oc], xV = vb[oc];
  const float* xb = x + b*8*HW;
  for (int ky = 0; ky < 3; ky++){
    int r = h+ky-1;
    if ((unsigned)r >= 96u) continue;
    for (int kx = 0; kx < 3; kx++){
      int c = w+kx-1;
      if ((unsigned)c >= 96u) continue;
      int off = r*96 + c;
      int wo  = ky*3 + kx;
      #pragma unroll
      for (int ic = 0; ic < 8; ic++){
        float a = xb[ic*HW + off];
        xU += a * uw[oc*72 + ic*9 + wo];
        xR += a * rw[oc*72 + ic*9 + wo];
        xV += a * vw[oc*72 + ic*9 + wo];
      }
    }
  }
  int pt = b*576 + (p >> 4), px = p & 15;
  const float* ur = g_urv + (size_t)pt*4608 + px;
  float gU = ur[(0*96 + oc)*16] + uwb[oc];
  float gR = ur[(1*96 + oc)*16] + rwb[oc];
  float gV = ur[(2*96 + oc)*16] + vwb[oc];
  float u = 1.f / (1.f + __expf(-(xU + gU)));
  float r = 1.f / (1.f + __expf(-(xR + gR)));
  float v = xV + r * gV;
  float oi = (v >= 0.f) ? v : 0.2f*v;
  float h0 = hp[(b*96 + oc)*HW + p];
  out[(b*96 + oc)*HW + p] = h0*u + oi*(1.f - u);
}

extern "C" void kernel_launch(void* const* d_in, const int* in_sizes, int n_in,
                              void* d_out, int out_size, void* d_ws, size_t ws_size,
                              hipStream_t stream){
  const float* x    = (const float*)d_in[0];
  const float* hp   = (const float*)d_in[1];
  const float* sw1  = (const float*)d_in[2];
  const float* sb1  = (const float*)d_in[3];
  const float* sw2  = (const float*)d_in[4];
  const float* sb2  = (const float*)d_in[5];
  const float* rw   = (const float*)d_in[6];
  const float* rb   = (const float*)d_in[7];
  const float* uw   = (const float*)d_in[8];
  const float* ub   = (const float*)d_in[9];
  const float* vw   = (const float*)d_in[10];
  const float* vb   = (const float*)d_in[11];
  const float* rww  = (const float*)d_in[12];
  const float* rwb  = (const float*)d_in[13];
  const float* uww  = (const float*)d_in[14];
  const float* uwb  = (const float*)d_in[15];
  const float* vww  = (const float*)d_in[16];
  const float* vwb  = (const float*)d_in[17];

  pack_b_k    <<<dim3((3*96*1248 + 255)/256), dim3(256), 0, stream>>>(uww, rww, vww);
  pack_w1b_k  <<<dim3((25*4*1024 + 255)/256), dim3(256), 0, stream>>>(sw1);
  transpose_k <<<dim3(288, 4, 4), dim3(256), 0, stream>>>(hp, x);
  conv1_mfma_k<<<dim3(144, 1, 4), dim3(512), 0, stream>>>(sb1);
  conv2_k     <<<dim3(72, 2, 4), dim3(256), 0, stream>>>(sw2, sb2);
  gemm_k      <<<dim3(576),      dim3(256), 0, stream>>>();
  gate_k      <<<dim3(36, 96, 4), dim3(256), 0, stream>>>(x, hp,
               uw, ub, rw, rb, vw, vb, uwb, rwb, vwb, (float*)d_out);
}

// Round 14
// 334.626 us; speedup vs baseline: 1.0242x; 1.0242x over previous
//
#include <hip/hip_runtime.h>
#include <hip/hip_bf16.h>

#define HW 9216      // 96*96

typedef unsigned short ushort;
typedef unsigned int   uint;
typedef __attribute__((ext_vector_type(4))) float f32x4;
typedef __attribute__((ext_vector_type(2))) uint  u32x2;
typedef __attribute__((ext_vector_type(4))) uint  u32x4;
typedef __attribute__((ext_vector_type(4))) int   i32x4;
typedef __attribute__((ext_vector_type(8))) short s16x8;
typedef __attribute__((ext_vector_type(8))) _Float16 f16x8;

// ---------------- module-global intermediates (BSS) ----------------
__device__ float  g_o1[4*32*HW];                 // conv1 out (bias+relu) fp32
__device__ float  g_q [4*4*26*HW];               // conv2 split-K=4 partials (bias in kg0)
__device__ float  g_qs[4*26*HW];                 // combined + relu'd flow fields
__device__ __align__(16) _Float16 g_hh[4*(size_t)HW*96]; // hp transposed fp16: [b][px][96ch] (gather table)
__device__ __align__(16) ushort g_chi[4*(size_t)HW*128]; // concat [x;hp] transposed, bf16 HI, ch-pad to 128
__device__ __align__(16) ushort g_clo[4*(size_t)HW*128]; // bf16 LO residual
__device__ __align__(16) ushort g_w1b[32*4*2048];        // conv1 W: [(tap*4+cb)][hl][nt][16oc][32k] bf16; taps 25..31 BSS-zero
__device__ __align__(16) ushort g_b[18*39*512];  // weights bf16, layout [nt][kb][lane=q*16+nl][8] (conflict-free)
__device__ __align__(16) float  g_urv[2304*288*16]; // GEMM out, tile-major [pt][n][16px]

__device__ __forceinline__ ushort f2b(float f){  // fp32 -> bf16 bits, RNE
  uint x = __float_as_uint(f);
  return (ushort)((x + 0x7FFFu + ((x >> 16) & 1u)) >> 16);
}
__device__ __forceinline__ float b2f(ushort h){
  return __uint_as_float(((uint)h) << 16);
}

// ---------------- K0: pack 1x1 weights into B-fragment layout
// K-ordering PERMUTED: k' = l*96 + c  (weight flat index = c*13 + l)
// Within (nt,kb): lane-linear fragments: ushort idx = ((kk>>3)*16 + nl)*8 + (kk&7)
__global__ void pack_b_k(const float* __restrict__ uww, const float* __restrict__ rww,
                         const float* __restrict__ vww){
  int i = blockIdx.x*256 + threadIdx.x;
  if (i >= 3*96*1248) return;
  int gate = i / (96*1248); int rem = i % (96*1248);
  int oc = rem / 1248;      int kp = rem % 1248;   // k' position
  int l = kp / 96, c = kp % 96;
  const float* src = (gate == 0) ? uww : ((gate == 1) ? rww : vww);
  float v = src[oc*1248 + c*13 + l];
  int n  = gate*96 + oc;
  int nt = n >> 4, nl = n & 15;
  int kb = kp >> 5, kk = kp & 31;
  g_b[(nt*39 + kb)*512 + ((kk >> 3)*16 + nl)*8 + (kk & 7)] = f2b(v);
}

// ---------------- K0a: pack conv1 weights -> bf16 hi/lo MFMA B-fragments
// sw1 layout: (32 oc, 104 ci, 5, 5). Pad ci to 128 with zeros (makes g_c* pad inert).
__global__ void pack_w1b_k(const float* __restrict__ w1){
  int i = blockIdx.x*256 + threadIdx.x;
  if (i >= 25*4*1024) return;
  int tap = i >> 12;
  int cb  = (i >> 10) & 3;
  int oc  = (i >> 5) & 31;
  int kk  = i & 31;
  int ci  = cb*32 + kk;
  float w = (ci < 104) ? w1[oc*2600 + ci*25 + tap] : 0.f;
  ushort h = f2b(w);
  float rem = w - b2f(h);
  int base = ((tap*4 + cb) << 11) + (oc >> 4)*512 + (oc & 15)*32 + kk;
  g_w1b[base]        = h;         // hi
  g_w1b[base + 1024] = f2b(rem);  // lo
}

// ---------------- K0b: transpose hp (B,C,HW) -> g_hh (fp16) + g_chi/g_clo (bf16, ch 8..103)
//                 blockIdx.y==3 handles x -> g_chi/g_clo ch 0..7
__global__ __launch_bounds__(256) void transpose_k(const float* __restrict__ hp,
                                                   const float* __restrict__ x){
  __shared__ float tile[32][33];
  int s0 = blockIdx.x*32;          // spatial tile
  int b  = blockIdx.z;
  int t  = threadIdx.x;
  if (blockIdx.y < 3){
    int c0 = blockIdx.y*32;        // channel tile (96 = 3*32)
    for (int i = t; i < 32*32; i += 256){
      int c = i >> 5, s = i & 31;
      tile[c][s] = hp[((size_t)(b*96 + c0 + c))*HW + s0 + s];
    }
    __syncthreads();
    for (int i = t; i < 32*32; i += 256){
      int s = i >> 5, c = i & 31;
      float v = tile[c][s];
      size_t px = (size_t)b*HW + s0 + s;
      g_hh[px*96 + c0 + c] = (_Float16)v;
      ushort h = f2b(v);
      g_chi[px*128 + 8 + c0 + c] = h;
      g_clo[px*128 + 8 + c0 + c] = f2b(v - b2f(h));
    }
  } else {
    for (int i = t; i < 8*32; i += 256){
      int c = i >> 5, s = i & 31;
      tile[c][s] = x[((size_t)(b*8 + c))*HW + s0 + s];
    }
    __syncthreads();
    for (int i = t; i < 32*8; i += 256){
      int s = i >> 3, c = i & 7;
      float v = tile[c][s];
      size_t px = (size_t)b*HW + s0 + s;
      ushort h = f2b(v);
      g_chi[px*128 + c] = h;
      g_clo[px*128 + c] = f2b(v - b2f(h));
    }
  }
}

// ---------------- K1: conv1 5x5 pad2 (104ch->32ch) via MFMA, 3-term bf16 split
// 8 waves/block (512 thr), split-K over taps: wave w owns taps 4w..4w+3
// (25 real taps padded to 32; pads have BSS-zero weights, clamped A-address).
__global__ __launch_bounds__(512) void conv1_mfma_k(const float* __restrict__ b1){
  __shared__ __align__(16) ushort sh[2*160*128];   // 80 KB; reused as 64 KB reduce buf
  int t = threadIdx.x;
  int w = t >> 6, lane = t & 63;
  int nl = lane & 15, q = lane >> 4;
  int rt = blockIdx.x / 6, ct = blockIdx.x % 6;    // 24 row-tiles x 6 col-tiles
  int b  = blockIdx.z;
  int r0 = rt*4, c0 = ct*16;
  const size_t pbase = (size_t)b*HW;

  // ---- cooperative stage: 5120 16B-chunks, 10 per thread, one exposure
  #pragma unroll
  for (int i = 0; i < 10; i++){
    int idx = i*512 + t;
    int half = (i >= 5) ? 1 : 0;                   // 0: hi (g_chi), 1: lo (g_clo)
    int rem = idx - half*2560;
    int px = rem >> 4, ci = rem & 15;
    int cs = ci ^ (px & 15);                       // source-chunk swizzle
    int r = px / 20, c = px - r*20;
    int gr = r0 + r - 2, gc = c0 + c - 2;
    f32x4 v = (f32x4){0.f,0.f,0.f,0.f};
    if ((unsigned)gr < 96u && (unsigned)gc < 96u){
      const ushort* src = half ? g_clo : g_chi;
      v = *(const f32x4*)(src + ((pbase + (size_t)(gr*96 + gc)) << 7) + cs*8);
    }
    *(f32x4*)((char*)sh + (size_t)idx*16) = v;     // linear LDS write: free
  }
  __syncthreads();

  // per-wave tap set: tp = 4w + i, i = 0..3 (static unroll; dead taps have zero B)
  int kxA[4], kyA[4], tpA[4];
  #pragma unroll
  for (int i = 0; i < 4; i++){
    int tp  = 4*w + i;
    int tpc = (tp > 24) ? 24 : tp;                 // clamp A-address; B is zero there
    kyA[i] = tpc / 5;
    kxA[i] = tpc - kyA[i]*5;
    tpA[i] = tp;
  }
  int foff = nl*32 + q*8;                          // B-frag lane offset (shorts)

  f32x4 acc[4][2];
  #pragma unroll
  for (int mr = 0; mr < 4; mr++){
    acc[mr][0] = (f32x4){0.f,0.f,0.f,0.f};
    acc[mr][1] = (f32x4){0.f,0.f,0.f,0.f};
  }

  for (int cb = 0; cb < 4; cb++){
    const ushort* bpc = g_w1b + ((size_t)cb << 11);
    s16x8 bq[3][4];
#define LOADB(slot, i) { const ushort* bp = bpc + ((size_t)tpA[i] << 13); \
    bq[slot][0] = *(const s16x8*)(bp + foff); \
    bq[slot][1] = *(const s16x8*)(bp + 512 + foff); \
    bq[slot][2] = *(const s16x8*)(bp + 1024 + foff); \
    bq[slot][3] = *(const s16x8*)(bp + 1536 + foff); }
    LOADB(0, 0); LOADB(1, 1);

    #pragma unroll
    for (int i = 0; i < 4; i++){
      if (i < 2) LOADB((i + 2) % 3, i + 2);        // static rotation (i is literal)
      int ky = kyA[i], kx = kxA[i];
      int chq = cb*4 + q;
      s16x8 ah[4], al[4];
      #pragma unroll
      for (int mr = 0; mr < 4; mr++){
        int px  = (mr + ky)*20 + kx + nl;
        int off = px*256 + (((chq ^ (px & 15))) << 4);
        ah[mr] = *(const s16x8*)((const char*)sh + off);
        al[mr] = *(const s16x8*)((const char*)sh + 40960 + off);
      }
      const int cur = i % 3;
      #pragma unroll
      for (int mr = 0; mr < 4; mr++){
        acc[mr][0] = __builtin_amdgcn_mfma_f32_16x16x32_bf16(ah[mr], bq[cur][0], acc[mr][0], 0,0,0);
        acc[mr][1] = __builtin_amdgcn_mfma_f32_16x16x32_bf16(ah[mr], bq[cur][1], acc[mr][1], 0,0,0);
      }
      #pragma unroll
      for (int mr = 0; mr < 4; mr++){
        acc[mr][0] = __builtin_amdgcn_mfma_f32_16x16x32_bf16(al[mr], bq[cur][0], acc[mr][0], 0,0,0);
        acc[mr][1] = __builtin_amdgcn_mfma_f32_16x16x32_bf16(al[mr], bq[cur][1], acc[mr][1], 0,0,0);
      }
      #pragma unroll
      for (int mr = 0; mr < 4; mr++){
        acc[mr][0] = __builtin_amdgcn_mfma_f32_16x16x32_bf16(ah[mr], bq[cur][2], acc[mr][0], 0,0,0);
        acc[mr][1] = __builtin_amdgcn_mfma_f32_16x16x32_bf16(ah[mr], bq[cur][3], acc[mr][1], 0,0,0);
      }
    }
#undef LOADB
  }

  // ---- cross-wave reduction through LDS (reuse halo buffer; 64 KB of 80)
  __syncthreads();
  float* red = (float*)sh;                         // slot(mr,nt,w): 1 KB each
  #pragma unroll
  for (int mr = 0; mr < 4; mr++)
    #pragma unroll
    for (int nt = 0; nt < 2; nt++)
      *(f32x4*)&red[(((mr*2 + nt)*8 + w) << 8) + lane*4] = acc[mr][nt];
  __syncthreads();

  int mr = w >> 1, nt = w & 1;                     // wave w finalizes (mr, nt)
  {
    f32x4 s = (f32x4){0.f,0.f,0.f,0.f};
    #pragma unroll
    for (int ww = 0; ww < 8; ww++)
      s += *(f32x4*)&red[(((mr*2 + nt)*8 + ww) << 8) + lane*4];
    int oc = nt*16 + nl;
    float bias = b1[oc];
    s.x = fmaxf(s.x + bias, 0.f); s.y = fmaxf(s.y + bias, 0.f);
    s.z = fmaxf(s.z + bias, 0.f); s.w = fmaxf(s.w + bias, 0.f);
    *(f32x4*)(g_o1 + ((size_t)(b*32 + oc))*HW + (size_t)(r0 + mr)*96 + c0 + q*4) = s;
  }
}

// ---------------- K3: conv2 5x5 pad2 (32ch->26ch), split-K=4 (8 ic each), bias in kg0
// 576 blocks (2.25/CU) — single stage + single barrier + single compute pass. [R12 form]
__global__ __launch_bounds__(256) void conv2_k(const float* __restrict__ wt2,
                                               const float* __restrict__ b2){
  __shared__ __align__(16) float in_sh[8][20][24];
  __shared__ __align__(16) float w_sh[8][25][32];
  int tile = blockIdx.x;
  int kg   = blockIdx.y;           // 0..3, owns ic 8*kg..8*kg+7
  int b    = blockIdx.z;
  int row0 = (tile / 6) * 16, col0 = (tile % 6) * 16;
  int t = threadIdx.x;
  int og  = t >> 5;
  int pos = t & 31;
  int row = pos >> 1, x0 = (pos & 1)*8;

  float acc[8][4];
  #pragma unroll
  for (int j = 0; j < 8; j++)
    #pragma unroll
    for (int o = 0; o < 4; o++) acc[j][o] = 0.f;

  for (int idx = t; idx < 8*20*24; idx += 256){
    int i = idx / 480, rem = idx % 480;
    int r = rem / 24, c = rem % 24;
    int gr = row0 + r - 2, gc = col0 + c - 2;
    float v = 0.f;
    if ((unsigned)gr < 96u && (unsigned)gc < 96u){
      int ci = kg*8 + i;
      v = g_o1[(b*32 + ci)*HW + gr*96 + gc];
    }
    in_sh[i][r][c] = v;
  }
  for (int idx = t; idx < 8*25*32; idx += 256){
    int i = idx / 800, rem = idx % 800;
    int tap = rem / 32, oc = rem % 32;
    int ci = kg*8 + i;
    w_sh[i][tap][oc] = (oc < 26) ? wt2[oc*800 + ci*25 + tap] : 0.f;
  }
  __syncthreads();

  for (int i = 0; i < 8; i++){
    #pragma unroll
    for (int ky = 0; ky < 5; ky++){
      const float* rp = &in_sh[i][row + ky][x0];
      f32x4 s0 = *(const f32x4*)(rp);
      f32x4 s1 = *(const f32x4*)(rp + 4);
      f32x4 s2 = *(const f32x4*)(rp + 8);
      float seg[12] = {s0.x,s0.y,s0.z,s0.w, s1.x,s1.y,s1.z,s1.w, s2.x,s2.y,s2.z,s2.w};
      #pragma unroll
      for (int kx = 0; kx < 5; kx++){
        f32x4 wv = *(const f32x4*)&w_sh[i][ky*5 + kx][og*4];
        #pragma unroll
        for (int j = 0; j < 8; j++){
          float a = seg[kx + j];
          acc[j][0] += a*wv.x; acc[j][1] += a*wv.y;
          acc[j][2] += a*wv.z; acc[j][3] += a*wv.w;
        }
      }
    }
  }

  int rg = row0 + row, cg = col0 + x0;
  #pragma unroll
  for (int o = 0; o < 4; o++){
    int slot = og*4 + o;
    if (slot < 26){
      float bias = (kg == 0) ? b2[slot] : 0.f;
      float* d = g_q + (size_t)kg*4*26*HW + ((size_t)(b*26 + slot))*HW + rg*96 + cg;
      #pragma unroll
      for (int j = 0; j < 8; j++) d[j] = acc[j][o] + bias;
    }
  }
}

// ---------------- K3b: combine conv2 partials: g_qs = relu(sum of 4 kg slices)
__global__ __launch_bounds__(256) void combine2_k(){
  const int NQ = 4*26*HW;
  int i = blockIdx.x*256 + threadIdx.x;
  if (i >= NQ) return;
  float s = g_q[i] + g_q[NQ + i] + g_q[2*NQ + i] + g_q[3*NQ + i];
  g_qs[i] = fmaxf(s, 0.f);
}

// ---------------- K5: FUSED sample + MFMA GEMM -> g_urv (tile-major)  [R9 structure]
// Prologue reads pre-combined, pre-relu'd g_qs (1 load/coord). XCD-pinned remap.
// l=12 plane exactly zero -> 36 bodies. fp16 gathers, fp32 weighting, RNE pack.
// Distance-1 pipeline, raw barriers (no vmcnt drain), conflict-free Bsh.
__global__ __launch_bounds__(256) void gemm_k(){
  __shared__ __align__(16) ushort Bsh[18*512];     // 18 KB, [nt][lane][8 ushorts]
  __shared__ __align__(16) float cw4[12][64][4];   // 12 KB: bilinear weights (z-folded)
  __shared__ __align__(16) int   co4[12][64][4];   // 12 KB: corner pixel offsets
  int t = threadIdx.x;
  int w = t >> 6, lane = t & 63;
  int nl = lane & 15, quad = lane >> 4;
  int L   = blockIdx.x;            // 0..575
  int blk = (L & 7)*72 + (L >> 3); // bijective XCD-pinned remap (576 = 8*72)
  int b   = blk / 144;             // 4 pt per block, 144 blocks per batch
  int pbase0 = (blk % 144) * 64;   // first pixel of this block's 64-px strip
  int pt  = blk*4 + w;

  // ---- prologue: weights/offsets for 64 px x 12 l (all 256 threads)
  for (int idx = t; idx < 768; idx += 256){
    int l = idx >> 6, m = idx & 63;
    int p = pbase0 + m;
    float gx = g_qs[(b*26 + l     )*HW + p];
    float gy = g_qs[(b*26 + 13 + l)*HW + p];
    float ix = gx * (96.f/95.f) - 0.5f;
    float iy = gy * (96.f/95.f) - 0.5f;
    float iz = (float)(l+1) * (13.f/12.f) - 0.5f;
    float z0 = floorf(iz);
    float zf = 0.f;
    #pragma unroll
    for (int dz = 0; dz < 2; dz++){
      float zc = z0 + (float)dz;
      float wz = 1.f - fabsf(iz - zc);
      if (zc >= 0.f && zc <= 12.f) zf += wz;
    }
    float x0f = floorf(ix), y0f = floorf(iy);
    #pragma unroll
    for (int dy = 0; dy < 2; dy++){
      float yc = y0f + (float)dy;
      float wy = 1.f - fabsf(iy - yc);
      bool  my = (yc >= 0.f) && (yc <= 95.f);
      int  yci = min(max((int)yc, 0), 95);
      #pragma unroll
      for (int dx = 0; dx < 2; dx++){
        float xc = x0f + (float)dx;
        float wx = 1.f - fabsf(ix - xc);
        bool  mx = (xc >= 0.f) && (xc <= 95.f);
        int  xci = min(max((int)xc, 0), 95);
        cw4[l][m][dy*2+dx] = (mx && my) ? zf*wy*wx : 0.f;
        co4[l][m][dy*2+dx] = yci*96 + xci;
      }
    }
  }

  f32x4 acc[18];
  #pragma unroll
  for (int nt = 0; nt < 18; nt++) acc[nt] = (f32x4){0.f,0.f,0.f,0.f};

  const u32x2* Bg8 = reinterpret_cast<const u32x2*>(g_b);
  const _Float16* hb = g_hh + (size_t)b*HW*96 + quad*8;  // + kb3*32 per iter
  int mloc = w*16 + nl;

  f16x8 gA[4], gB[4];
  f32x4 wA, wB;
  u32x2 sA[9], sB[9];

  // stage kb=0 (independent of cw4) — issued before the publishing barrier
  #pragma unroll
  for (int u = 0; u < 9; u++){
    int idx8 = u*256 + t;
    sA[u] = Bg8[((idx8 >> 7)*39 + 0)*128 + (idx8 & 127)];
  }
  __syncthreads();                 // publish cw4/co4 (one-time full drain, OK)

  // gather kb=0 (l=0, kb3=0) into set A
  {
    wA = *(const f32x4*)cw4[0][mloc];
    i32x4 ov_ = *(const i32x4*)co4[0][mloc];
    gA[0] = *(const f16x8*)(hb + (size_t)ov_.x*96);
    gA[1] = *(const f16x8*)(hb + (size_t)ov_.y*96);
    gA[2] = *(const f16x8*)(hb + (size_t)ov_.z*96);
    gA[3] = *(const f16x8*)(hb + (size_t)ov_.w*96);
  }
  int ln = 0, k3n = 1;             // (l, kb3) of kb+1

#define BODY(KB, GC, WC, GN, WN, SC, SN, PF) { \
  if (PF){ \
    _Pragma("unroll") \
    for (int u = 0; u < 9; u++){ \
      int idx8 = u*256 + t; \
      SN[u] = Bg8[((idx8 >> 7)*39 + (KB) + 1)*128 + (idx8 & 127)]; \
    } \
    WN = *(const f32x4*)cw4[ln][mloc]; \
    i32x4 ov_ = *(const i32x4*)co4[ln][mloc]; \
    const _Float16* hc_ = hb + k3n*32; \
    GN[0] = *(const f16x8*)(hc_ + (size_t)ov_.x*96); \
    GN[1] = *(const f16x8*)(hc_ + (size_t)ov_.y*96); \
    GN[2] = *(const f16x8*)(hc_ + (size_t)ov_.z*96); \
    GN[3] = *(const f16x8*)(hc_ + (size_t)ov_.w*96); \
    k3n++; if (k3n == 3){ k3n = 0; ln++; } \
  } \
  _Pragma("unroll") \
  for (int u = 0; u < 9; u++){ \
    int idx8 = u*256 + t; \
    *(u32x2*)((char*)Bsh + idx8*8) = SC[u]; \
  } \
  float av[8]; \
  _Pragma("unroll") \
  for (int j = 0; j < 8; j++) \
    av[j] = WC.x*(float)GC[0][j] + WC.y*(float)GC[1][j] \
          + WC.z*(float)GC[2][j] + WC.w*(float)GC[3][j]; \
  union { u32x4 u4; s16x8 s8v; } cv_; \
  cv_.u4.x = (uint)f2b(av[0]) | ((uint)f2b(av[1]) << 16); \
  cv_.u4.y = (uint)f2b(av[2]) | ((uint)f2b(av[3]) << 16); \
  cv_.u4.z = (uint)f2b(av[4]) | ((uint)f2b(av[5]) << 16); \
  cv_.u4.w = (uint)f2b(av[6]) | ((uint)f2b(av[7]) << 16); \
  asm volatile("s_waitcnt lgkmcnt(0)" ::: "memory"); \
  __builtin_amdgcn_s_barrier(); \
  asm volatile("" ::: "memory"); \
  _Pragma("unroll") \
  for (int nt = 0; nt < 18; nt++){ \
    s16x8 bf = *(const s16x8*)((const char*)Bsh + nt*1024 + lane*16); \
    acc[nt] = __builtin_amdgcn_mfma_f32_16x16x32_bf16(cv_.s8v, bf, acc[nt], 0, 0, 0); \
  } \
  asm volatile("" ::: "memory"); \
  __builtin_amdgcn_s_barrier(); \
  asm volatile("" ::: "memory"); \
}

  for (int kb = 0; kb < 34; kb += 2){
    BODY(kb,     gA, wA, gB, wB, sA, sB, 1);
    BODY(kb + 1, gB, wB, gA, wA, sB, sA, 1);
  }
  BODY(34, gA, wA, gB, wB, sA, sB, 1);
  BODY(35, gB, wB, gA, wA, sB, sA, 0);
#undef BODY

  float* dst = g_urv + (size_t)pt*4608;          // [pt][n=288][px=16]
  #pragma unroll
  for (int nt = 0; nt < 18; nt++)
    *(f32x4*)&dst[(nt*16 + nl)*16 + quad*4] = acc[nt];
}

// ---------------- K6: fused 3x3 convs on x + gating -> out
__global__ __launch_bounds__(256) void gate_k(const float* __restrict__ x,
                        const float* __restrict__ hp,
                        const float* __restrict__ uw, const float* __restrict__ ub,
                        const float* __restrict__ rw, const float* __restrict__ rb,
                        const float* __restrict__ vw, const float* __restrict__ vb,
                        const float* __restrict__ uwb, const float* __restrict__ rwb,
                        const float* __restrict__ vwb, float* __restrict__ out){
  int p  = blockIdx.x*256 + threadIdx.x;
  int oc = blockIdx.y;
  int b  = blockIdx.z;
  int h = p/96, w = p%96;
  float xU = ub[oc], xR = rb[oc], xV = vb[oc];
  const float* xb = x + b*8*HW;
  for (int ky = 0; ky < 3; ky++){
    int r = h+ky-1;
    if ((unsigned)r >= 96u) continue;
    for (int kx = 0; kx < 3; kx++){
      int c = w+kx-1;
      if ((unsigned)c >= 96u) continue;
      int off = r*96 + c;
      int wo  = ky*3 + kx;
      #pragma unroll
      for (int ic = 0; ic < 8; ic++){
        float a = xb[ic*HW + off];
        xU += a * uw[oc*72 + ic*9 + wo];
        xR += a * rw[oc*72 + ic*9 + wo];
        xV += a * vw[oc*72 + ic*9 + wo];
      }
    }
  }
  int pt = b*576 + (p >> 4), px = p & 15;
  const float* ur = g_urv + (size_t)pt*4608 + px;
  float gU = ur[(0*96 + oc)*16] + uwb[oc];
  float gR = ur[(1*96 + oc)*16] + rwb[oc];
  float gV = ur[(2*96 + oc)*16] + vwb[oc];
  float u = 1.f / (1.f + __expf(-(xU + gU)));
  float r = 1.f / (1.f + __expf(-(xR + gR)));
  float v = xV + r * gV;
  float oi = (v >= 0.f) ? v : 0.2f*v;
  float h0 = hp[(b*96 + oc)*HW + p];
  out[(b*96 + oc)*HW + p] = h0*u + oi*(1.f - u);
}

extern "C" void kernel_launch(void* const* d_in, const int* in_sizes, int n_in,
                              void* d_out, int out_size, void* d_ws, size_t ws_size,
                              hipStream_t stream){
  const float* x    = (const float*)d_in[0];
  const float* hp   = (const float*)d_in[1];
  const float* sw1  = (const float*)d_in[2];
  const float* sb1  = (const float*)d_in[3];
  const float* sw2  = (const float*)d_in[4];
  const float* sb2  = (const float*)d_in[5];
  const float* rw   = (const float*)d_in[6];
  const float* rb   = (const float*)d_in[7];
  const float* uw   = (const float*)d_in[8];
  const float* ub   = (const float*)d_in[9];
  const float* vw   = (const float*)d_in[10];
  const float* vb   = (const float*)d_in[11];
  const float* rww  = (const float*)d_in[12];
  const float* rwb  = (const float*)d_in[13];
  const float* uww  = (const float*)d_in[14];
  const float* uwb  = (const float*)d_in[15];
  const float* vww  = (const float*)d_in[16];
  const float* vwb  = (const float*)d_in[17];

  pack_b_k    <<<dim3((3*96*1248 + 255)/256), dim3(256), 0, stream>>>(uww, rww, vww);
  pack_w1b_k  <<<dim3((25*4*1024 + 255)/256), dim3(256), 0, stream>>>(sw1);
  transpose_k <<<dim3(288, 4, 4), dim3(256), 0, stream>>>(hp, x);
  conv1_mfma_k<<<dim3(144, 1, 4), dim3(512), 0, stream>>>(sb1);
  conv2_k     <<<dim3(36, 4, 4), dim3(256), 0, stream>>>(sw2, sb2);
  combine2_k  <<<dim3((4*26*HW + 255)/256), dim3(256), 0, stream>>>();
  gemm_k      <<<dim3(576),      dim3(256), 0, stream>>>();
  gate_k      <<<dim3(36, 96, 4), dim3(256), 0, stream>>>(x, hp,
               uw, ub, rw, rb, vw, vb, uwb, rwb, vwb, (float*)d_out);
}

// Round 15
// 323.166 us; speedup vs baseline: 1.0605x; 1.0355x over previous
//
#include <hip/hip_runtime.h>
#include <hip/hip_bf16.h>

#define HW 9216      // 96*96

typedef unsigned short ushort;
typedef unsigned int   uint;
typedef __attribute__((ext_vector_type(4))) float f32x4;
typedef __attribute__((ext_vector_type(2))) uint  u32x2;
typedef __attribute__((ext_vector_type(4))) uint  u32x4;
typedef __attribute__((ext_vector_type(4))) int   i32x4;
typedef __attribute__((ext_vector_type(8))) short s16x8;
typedef __attribute__((ext_vector_type(8))) _Float16 f16x8;

// ---------------- module-global intermediates (BSS) ----------------
__device__ float  g_o1[4*32*HW];                 // conv1 out (bias+relu) fp32
__device__ float  g_q [4*4*26*HW];               // conv2 split-K=4 partials (bias in kg0)
__device__ __align__(16) _Float16 g_hh[4*(size_t)HW*96]; // hp transposed fp16: [b][px][96ch] (gather table)
__device__ __align__(16) ushort g_chi[4*(size_t)HW*128]; // concat [x;hp] transposed, bf16 HI, ch-pad to 128
__device__ __align__(16) ushort g_clo[4*(size_t)HW*128]; // bf16 LO residual
__device__ __align__(16) ushort g_w1b[32*4*2048];        // conv1 W: [(tap*4+cb)][hl][nt][16oc][32k] bf16; taps 25..31 BSS-zero
__device__ __align__(16) ushort g_b[18*39*512];  // weights bf16, layout [nt][kb][lane=q*16+nl][8] (conflict-free)
__device__ __align__(16) float  g_urv[2304*288*16]; // GEMM out, tile-major [pt][n][16px]

__device__ __forceinline__ ushort f2b(float f){  // fp32 -> bf16 bits, RNE
  uint x = __float_as_uint(f);
  return (ushort)((x + 0x7FFFu + ((x >> 16) & 1u)) >> 16);
}
__device__ __forceinline__ float b2f(ushort h){
  return __uint_as_float(((uint)h) << 16);
}

// ---------------- K0: pack 1x1 weights into B-fragment layout
// K-ordering PERMUTED: k' = l*96 + c  (weight flat index = c*13 + l)
// Within (nt,kb): lane-linear fragments: ushort idx = ((kk>>3)*16 + nl)*8 + (kk&7)
__global__ void pack_b_k(const float* __restrict__ uww, const float* __restrict__ rww,
                         const float* __restrict__ vww){
  int i = blockIdx.x*256 + threadIdx.x;
  if (i >= 3*96*1248) return;
  int gate = i / (96*1248); int rem = i % (96*1248);
  int oc = rem / 1248;      int kp = rem % 1248;   // k' position
  int l = kp / 96, c = kp % 96;
  const float* src = (gate == 0) ? uww : ((gate == 1) ? rww : vww);
  float v = src[oc*1248 + c*13 + l];
  int n  = gate*96 + oc;
  int nt = n >> 4, nl = n & 15;
  int kb = kp >> 5, kk = kp & 31;
  g_b[(nt*39 + kb)*512 + ((kk >> 3)*16 + nl)*8 + (kk & 7)] = f2b(v);
}

// ---------------- K0a: pack conv1 weights -> bf16 hi/lo MFMA B-fragments
// sw1 layout: (32 oc, 104 ci, 5, 5). Pad ci to 128 with zeros (makes g_c* pad inert).
__global__ void pack_w1b_k(const float* __restrict__ w1){
  int i = blockIdx.x*256 + threadIdx.x;
  if (i >= 25*4*1024) return;
  int tap = i >> 12;
  int cb  = (i >> 10) & 3;
  int oc  = (i >> 5) & 31;
  int kk  = i & 31;
  int ci  = cb*32 + kk;
  float w = (ci < 104) ? w1[oc*2600 + ci*25 + tap] : 0.f;
  ushort h = f2b(w);
  float rem = w - b2f(h);
  int base = ((tap*4 + cb) << 11) + (oc >> 4)*512 + (oc & 15)*32 + kk;
  g_w1b[base]        = h;         // hi
  g_w1b[base + 1024] = f2b(rem);  // lo
}

// ---------------- K0b: transpose hp (B,C,HW) -> g_hh (fp16) + g_chi/g_clo (bf16, ch 8..103)
//                 blockIdx.y==3 handles x -> g_chi/g_clo ch 0..7
__global__ __launch_bounds__(256) void transpose_k(const float* __restrict__ hp,
                                                   const float* __restrict__ x){
  __shared__ float tile[32][33];
  int s0 = blockIdx.x*32;          // spatial tile
  int b  = blockIdx.z;
  int t  = threadIdx.x;
  if (blockIdx.y < 3){
    int c0 = blockIdx.y*32;        // channel tile (96 = 3*32)
    for (int i = t; i < 32*32; i += 256){
      int c = i >> 5, s = i & 31;
      tile[c][s] = hp[((size_t)(b*96 + c0 + c))*HW + s0 + s];
    }
    __syncthreads();
    for (int i = t; i < 32*32; i += 256){
      int s = i >> 5, c = i & 31;
      float v = tile[c][s];
      size_t px = (size_t)b*HW + s0 + s;
      g_hh[px*96 + c0 + c] = (_Float16)v;
      ushort h = f2b(v);
      g_chi[px*128 + 8 + c0 + c] = h;
      g_clo[px*128 + 8 + c0 + c] = f2b(v - b2f(h));
    }
  } else {
    for (int i = t; i < 8*32; i += 256){
      int c = i >> 5, s = i & 31;
      tile[c][s] = x[((size_t)(b*8 + c))*HW + s0 + s];
    }
    __syncthreads();
    for (int i = t; i < 32*8; i += 256){
      int s = i >> 3, c = i & 7;
      float v = tile[c][s];
      size_t px = (size_t)b*HW + s0 + s;
      ushort h = f2b(v);
      g_chi[px*128 + c] = h;
      g_clo[px*128 + c] = f2b(v - b2f(h));
    }
  }
}

// ---------------- K1: conv1 5x5 pad2 (104ch->32ch) via MFMA, 3-term bf16 split
// 8 waves/block (512 thr), split-K over taps: wave w owns taps 4w..4w+3
// (25 real taps padded to 32; pads have BSS-zero weights, clamped A-address).
__global__ __launch_bounds__(512) void conv1_mfma_k(const float* __restrict__ b1){
  __shared__ __align__(16) ushort sh[2*160*128];   // 80 KB; reused as 64 KB reduce buf
  int t = threadIdx.x;
  int w = t >> 6, lane = t & 63;
  int nl = lane & 15, q = lane >> 4;
  int rt = blockIdx.x / 6, ct = blockIdx.x % 6;    // 24 row-tiles x 6 col-tiles
  int b  = blockIdx.z;
  int r0 = rt*4, c0 = ct*16;
  const size_t pbase = (size_t)b*HW;

  // ---- cooperative stage: 5120 16B-chunks, 10 per thread, one exposure
  #pragma unroll
  for (int i = 0; i < 10; i++){
    int idx = i*512 + t;
    int half = (i >= 5) ? 1 : 0;                   // 0: hi (g_chi), 1: lo (g_clo)
    int rem = idx - half*2560;
    int px = rem >> 4, ci = rem & 15;
    int cs = ci ^ (px & 15);                       // source-chunk swizzle
    int r = px / 20, c = px - r*20;
    int gr = r0 + r - 2, gc = c0 + c - 2;
    f32x4 v = (f32x4){0.f,0.f,0.f,0.f};
    if ((unsigned)gr < 96u && (unsigned)gc < 96u){
      const ushort* src = half ? g_clo : g_chi;
      v = *(const f32x4*)(src + ((pbase + (size_t)(gr*96 + gc)) << 7) + cs*8);
    }
    *(f32x4*)((char*)sh + (size_t)idx*16) = v;     // linear LDS write: free
  }
  __syncthreads();

  // per-wave tap set: tp = 4w + i, i = 0..3 (static unroll; dead taps have zero B)
  int kxA[4], kyA[4], tpA[4];
  #pragma unroll
  for (int i = 0; i < 4; i++){
    int tp  = 4*w + i;
    int tpc = (tp > 24) ? 24 : tp;                 // clamp A-address; B is zero there
    kyA[i] = tpc / 5;
    kxA[i] = tpc - kyA[i]*5;
    tpA[i] = tp;
  }
  int foff = nl*32 + q*8;                          // B-frag lane offset (shorts)

  f32x4 acc[4][2];
  #pragma unroll
  for (int mr = 0; mr < 4; mr++){
    acc[mr][0] = (f32x4){0.f,0.f,0.f,0.f};
    acc[mr][1] = (f32x4){0.f,0.f,0.f,0.f};
  }

  for (int cb = 0; cb < 4; cb++){
    const ushort* bpc = g_w1b + ((size_t)cb << 11);
    s16x8 bq[3][4];
#define LOADB(slot, i) { const ushort* bp = bpc + ((size_t)tpA[i] << 13); \
    bq[slot][0] = *(const s16x8*)(bp + foff); \
    bq[slot][1] = *(const s16x8*)(bp + 512 + foff); \
    bq[slot][2] = *(const s16x8*)(bp + 1024 + foff); \
    bq[slot][3] = *(const s16x8*)(bp + 1536 + foff); }
    LOADB(0, 0); LOADB(1, 1);

    #pragma unroll
    for (int i = 0; i < 4; i++){
      if (i < 2) LOADB((i + 2) % 3, i + 2);        // static rotation (i is literal)
      int ky = kyA[i], kx = kxA[i];
      int chq = cb*4 + q;
      s16x8 ah[4], al[4];
      #pragma unroll
      for (int mr = 0; mr < 4; mr++){
        int px  = (mr + ky)*20 + kx + nl;
        int off = px*256 + (((chq ^ (px & 15))) << 4);
        ah[mr] = *(const s16x8*)((const char*)sh + off);
        al[mr] = *(const s16x8*)((const char*)sh + 40960 + off);
      }
      const int cur = i % 3;
      #pragma unroll
      for (int mr = 0; mr < 4; mr++){
        acc[mr][0] = __builtin_amdgcn_mfma_f32_16x16x32_bf16(ah[mr], bq[cur][0], acc[mr][0], 0,0,0);
        acc[mr][1] = __builtin_amdgcn_mfma_f32_16x16x32_bf16(ah[mr], bq[cur][1], acc[mr][1], 0,0,0);
      }
      #pragma unroll
      for (int mr = 0; mr < 4; mr++){
        acc[mr][0] = __builtin_amdgcn_mfma_f32_16x16x32_bf16(al[mr], bq[cur][0], acc[mr][0], 0,0,0);
        acc[mr][1] = __builtin_amdgcn_mfma_f32_16x16x32_bf16(al[mr], bq[cur][1], acc[mr][1], 0,0,0);
      }
      #pragma unroll
      for (int mr = 0; mr < 4; mr++){
        acc[mr][0] = __builtin_amdgcn_mfma_f32_16x16x32_bf16(ah[mr], bq[cur][2], acc[mr][0], 0,0,0);
        acc[mr][1] = __builtin_amdgcn_mfma_f32_16x16x32_bf16(ah[mr], bq[cur][3], acc[mr][1], 0,0,0);
      }
    }
#undef LOADB
  }

  // ---- cross-wave reduction through LDS (reuse halo buffer; 64 KB of 80)
  __syncthreads();
  float* red = (float*)sh;                         // slot(mr,nt,w): 1 KB each
  #pragma unroll
  for (int mr = 0; mr < 4; mr++)
    #pragma unroll
    for (int nt = 0; nt < 2; nt++)
      *(f32x4*)&red[(((mr*2 + nt)*8 + w) << 8) + lane*4] = acc[mr][nt];
  __syncthreads();

  int mr = w >> 1, nt = w & 1;                     // wave w finalizes (mr, nt)
  {
    f32x4 s = (f32x4){0.f,0.f,0.f,0.f};
    #pragma unroll
    for (int ww = 0; ww < 8; ww++)
      s += *(f32x4*)&red[(((mr*2 + nt)*8 + ww) << 8) + lane*4];
    int oc = nt*16 + nl;
    float bias = b1[oc];
    s.x = fmaxf(s.x + bias, 0.f); s.y = fmaxf(s.y + bias, 0.f);
    s.z = fmaxf(s.z + bias, 0.f); s.w = fmaxf(s.w + bias, 0.f);
    *(f32x4*)(g_o1 + ((size_t)(b*32 + oc))*HW + (size_t)(r0 + mr)*96 + c0 + q*4) = s;
  }
}

// ---------------- K3: conv2 5x5 pad2 (32ch->26ch), split-K=4 (8 ic each), bias in kg0
// 576 blocks (2.25/CU) — single stage + single barrier + single compute pass.
__global__ __launch_bounds__(256) void conv2_k(const float* __restrict__ wt2,
                                               const float* __restrict__ b2){
  __shared__ __align__(16) float in_sh[8][20][24];
  __shared__ __align__(16) float w_sh[8][25][32];
  int tile = blockIdx.x;
  int kg   = blockIdx.y;           // 0..3, owns ic 8*kg..8*kg+7
  int b    = blockIdx.z;
  int row0 = (tile / 6) * 16, col0 = (tile % 6) * 16;
  int t = threadIdx.x;
  int og  = t >> 5;
  int pos = t & 31;
  int row = pos >> 1, x0 = (pos & 1)*8;

  float acc[8][4];
  #pragma unroll
  for (int j = 0; j < 8; j++)
    #pragma unroll
    for (int o = 0; o < 4; o++) acc[j][o] = 0.f;

  for (int idx = t; idx < 8*20*24; idx += 256){
    int i = idx / 480, rem = idx % 480;
    int r = rem / 24, c = rem % 24;
    int gr = row0 + r - 2, gc = col0 + c - 2;
    float v = 0.f;
    if ((unsigned)gr < 96u && (unsigned)gc < 96u){
      int ci = kg*8 + i;
      v = g_o1[(b*32 + ci)*HW + gr*96 + gc];
    }
    in_sh[i][r][c] = v;
  }
  for (int idx = t; idx < 8*25*32; idx += 256){
    int i = idx / 800, rem = idx % 800;
    int tap = rem / 32, oc = rem % 32;
    int ci = kg*8 + i;
    w_sh[i][tap][oc] = (oc < 26) ? wt2[oc*800 + ci*25 + tap] : 0.f;
  }
  __syncthreads();

  for (int i = 0; i < 8; i++){
    #pragma unroll
    for (int ky = 0; ky < 5; ky++){
      const float* rp = &in_sh[i][row + ky][x0];
      f32x4 s0 = *(const f32x4*)(rp);
      f32x4 s1 = *(const f32x4*)(rp + 4);
      f32x4 s2 = *(const f32x4*)(rp + 8);
      float seg[12] = {s0.x,s0.y,s0.z,s0.w, s1.x,s1.y,s1.z,s1.w, s2.x,s2.y,s2.z,s2.w};
      #pragma unroll
      for (int kx = 0; kx < 5; kx++){
        f32x4 wv = *(const f32x4*)&w_sh[i][ky*5 + kx][og*4];
        #pragma unroll
        for (int j = 0; j < 8; j++){
          float a = seg[kx + j];
          acc[j][0] += a*wv.x; acc[j][1] += a*wv.y;
          acc[j][2] += a*wv.z; acc[j][3] += a*wv.w;
        }
      }
    }
  }

  int rg = row0 + row, cg = col0 + x0;
  #pragma unroll
  for (int o = 0; o < 4; o++){
    int slot = og*4 + o;
    if (slot < 26){
      float bias = (kg == 0) ? b2[slot] : 0.f;
      float* d = g_q + (size_t)kg*4*26*HW + ((size_t)(b*26 + slot))*HW + rg*96 + cg;
      #pragma unroll
      for (int j = 0; j < 8; j++) d[j] = acc[j][o] + bias;
    }
  }
}

// ---------------- K5: FUSED sample + MFMA GEMM -> g_urv (tile-major)  [R9 structure]
// XCD-pinned block remap. Prologue sums 4 g_q slices in-place (overlaps B-staging).
// l=12 plane exactly zero -> 36 bodies. fp16 gathers, fp32 weighting, RNE pack.
// Distance-1 pipeline, raw barriers (no vmcnt drain), conflict-free Bsh.
__global__ __launch_bounds__(256) void gemm_k(){
  __shared__ __align__(16) ushort Bsh[18*512];     // 18 KB, [nt][lane][8 ushorts]
  __shared__ __align__(16) float cw4[12][64][4];   // 12 KB: bilinear weights (z-folded)
  __shared__ __align__(16) int   co4[12][64][4];   // 12 KB: corner pixel offsets
  int t = threadIdx.x;
  int w = t >> 6, lane = t & 63;
  int nl = lane & 15, quad = lane >> 4;
  int L   = blockIdx.x;            // 0..575
  int blk = (L & 7)*72 + (L >> 3); // bijective XCD-pinned remap (576 = 8*72)
  int b   = blk / 144;             // 4 pt per block, 144 blocks per batch
  int pbase0 = (blk % 144) * 64;   // first pixel of this block's 64-px strip
  int pt  = blk*4 + w;

  // ---- prologue: weights/offsets for 64 px x 12 l (all 256 threads)
  const int NQ = 4*26*HW;
  for (int idx = t; idx < 768; idx += 256){
    int l = idx >> 6, m = idx & 63;
    int p = pbase0 + m;
    int base = (b*26 + l)*HW + p;
    float gx = fmaxf(g_q[base] + g_q[NQ + base] + g_q[2*NQ + base] + g_q[3*NQ + base], 0.f);
    int base2 = (b*26 + 13 + l)*HW + p;
    float gy = fmaxf(g_q[base2] + g_q[NQ + base2] + g_q[2*NQ + base2] + g_q[3*NQ + base2], 0.f);
    float ix = gx * (96.f/95.f) - 0.5f;
    float iy = gy * (96.f/95.f) - 0.5f;
    float iz = (float)(l+1) * (13.f/12.f) - 0.5f;
    float z0 = floorf(iz);
    float zf = 0.f;
    #pragma unroll
    for (int dz = 0; dz < 2; dz++){
      float zc = z0 + (float)dz;
      float wz = 1.f - fabsf(iz - zc);
      if (zc >= 0.f && zc <= 12.f) zf += wz;
    }
    float x0f = floorf(ix), y0f = floorf(iy);
    #pragma unroll
    for (int dy = 0; dy < 2; dy++){
      float yc = y0f + (float)dy;
      float wy = 1.f - fabsf(iy - yc);
      bool  my = (yc >= 0.f) && (yc <= 95.f);
      int  yci = min(max((int)yc, 0), 95);
      #pragma unroll
      for (int dx = 0; dx < 2; dx++){
        float xc = x0f + (float)dx;
        float wx = 1.f - fabsf(ix - xc);
        bool  mx = (xc >= 0.f) && (xc <= 95.f);
        int  xci = min(max((int)xc, 0), 95);
        cw4[l][m][dy*2+dx] = (mx && my) ? zf*wy*wx : 0.f;
        co4[l][m][dy*2+dx] = yci*96 + xci;
      }
    }
  }

  f32x4 acc[18];
  #pragma unroll
  for (int nt = 0; nt < 18; nt++) acc[nt] = (f32x4){0.f,0.f,0.f,0.f};

  const u32x2* Bg8 = reinterpret_cast<const u32x2*>(g_b);
  const _Float16* hb = g_hh + (size_t)b*HW*96 + quad*8;  // + kb3*32 per iter
  int mloc = w*16 + nl;

  f16x8 gA[4], gB[4];
  f32x4 wA, wB;
  u32x2 sA[9], sB[9];

  // stage kb=0 (independent of cw4) — issued before the publishing barrier
  #pragma unroll
  for (int u = 0; u < 9; u++){
    int idx8 = u*256 + t;
    sA[u] = Bg8[((idx8 >> 7)*39 + 0)*128 + (idx8 & 127)];
  }
  __syncthreads();                 // publish cw4/co4 (one-time full drain, OK)

  // gather kb=0 (l=0, kb3=0) into set A
  {
    wA = *(const f32x4*)cw4[0][mloc];
    i32x4 ov_ = *(const i32x4*)co4[0][mloc];
    gA[0] = *(const f16x8*)(hb + (size_t)ov_.x*96);
    gA[1] = *(const f16x8*)(hb + (size_t)ov_.y*96);
    gA[2] = *(const f16x8*)(hb + (size_t)ov_.z*96);
    gA[3] = *(const f16x8*)(hb + (size_t)ov_.w*96);
  }
  int ln = 0, k3n = 1;             // (l, kb3) of kb+1

#define BODY(KB, GC, WC, GN, WN, SC, SN, PF) { \
  if (PF){ \
    _Pragma("unroll") \
    for (int u = 0; u < 9; u++){ \
      int idx8 = u*256 + t; \
      SN[u] = Bg8[((idx8 >> 7)*39 + (KB) + 1)*128 + (idx8 & 127)]; \
    } \
    WN = *(const f32x4*)cw4[ln][mloc]; \
    i32x4 ov_ = *(const i32x4*)co4[ln][mloc]; \
    const _Float16* hc_ = hb + k3n*32; \
    GN[0] = *(const f16x8*)(hc_ + (size_t)ov_.x*96); \
    GN[1] = *(const f16x8*)(hc_ + (size_t)ov_.y*96); \
    GN[2] = *(const f16x8*)(hc_ + (size_t)ov_.z*96); \
    GN[3] = *(const f16x8*)(hc_ + (size_t)ov_.w*96); \
    k3n++; if (k3n == 3){ k3n = 0; ln++; } \
  } \
  _Pragma("unroll") \
  for (int u = 0; u < 9; u++){ \
    int idx8 = u*256 + t; \
    *(u32x2*)((char*)Bsh + idx8*8) = SC[u]; \
  } \
  float av[8]; \
  _Pragma("unroll") \
  for (int j = 0; j < 8; j++) \
    av[j] = WC.x*(float)GC[0][j] + WC.y*(float)GC[1][j] \
          + WC.z*(float)GC[2][j] + WC.w*(float)GC[3][j]; \
  union { u32x4 u4; s16x8 s8v; } cv_; \
  cv_.u4.x = (uint)f2b(av[0]) | ((uint)f2b(av[1]) << 16); \
  cv_.u4.y = (uint)f2b(av[2]) | ((uint)f2b(av[3]) << 16); \
  cv_.u4.z = (uint)f2b(av[4]) | ((uint)f2b(av[5]) << 16); \
  cv_.u4.w = (uint)f2b(av[6]) | ((uint)f2b(av[7]) << 16); \
  asm volatile("s_waitcnt lgkmcnt(0)" ::: "memory"); \
  __builtin_amdgcn_s_barrier(); \
  asm volatile("" ::: "memory"); \
  _Pragma("unroll") \
  for (int nt = 0; nt < 18; nt++){ \
    s16x8 bf = *(const s16x8*)((const char*)Bsh + nt*1024 + lane*16); \
    acc[nt] = __builtin_amdgcn_mfma_f32_16x16x32_bf16(cv_.s8v, bf, acc[nt], 0, 0, 0); \
  } \
  asm volatile("" ::: "memory"); \
  __builtin_amdgcn_s_barrier(); \
  asm volatile("" ::: "memory"); \
}

  for (int kb = 0; kb < 34; kb += 2){
    BODY(kb,     gA, wA, gB, wB, sA, sB, 1);
    BODY(kb + 1, gB, wB, gA, wA, sB, sA, 1);
  }
  BODY(34, gA, wA, gB, wB, sA, sB, 1);
  BODY(35, gB, wB, gA, wA, sB, sA, 0);
#undef BODY

  float* dst = g_urv + (size_t)pt*4608;          // [pt][n=288][px=16]
  #pragma unroll
  for (int nt = 0; nt < 18; nt++)
    *(f32x4*)&dst[(nt*16 + nl)*16 + quad*4] = acc[nt];
}

// ---------------- K6: fused 3x3 convs on x + gating -> out
__global__ __launch_bounds__(256) void gate_k(const float* __restrict__ x,
                        const float* __restrict__ hp,
                        const float* __restrict__ uw, const float* __restrict__ ub,
                        const float* __restrict__ rw, const float* __restrict__ rb,
                        const float* __restrict__ vw, const float* __restrict__ vb,
                        const float* __restrict__ uwb, const float* __restrict__ rwb,
                        const float* __restrict__ vwb, float* __restrict__ out){
  int p  = blockIdx.x*256 + threadIdx.x;
  int oc = blockIdx.y;
  int b  = blockIdx.z;
  int h = p/96, w = p%96;
  float xU = ub[oc], xR = rb[oc], xV = vb[oc];
  const float* xb = x + b*8*HW;
  for (int ky = 0; ky < 3; ky++){
    int r = h+ky-1;
    if ((unsigned)r >= 96u) continue;
    for (int kx = 0; kx < 3; kx++){
      int c = w+kx-1;
      if ((unsigned)c >= 96u) continue;
      int off = r*96 + c;
      int wo  = ky*3 + kx;
      #pragma unroll
      for (int ic = 0; ic < 8; ic++){
        float a = xb[ic*HW + off];
        xU += a * uw[oc*72 + ic*9 + wo];
        xR += a * rw[oc*72 + ic*9 + wo];
        xV += a * vw[oc*72 + ic*9 + wo];
      }
    }
  }
  int pt = b*576 + (p >> 4), px = p & 15;
  const float* ur = g_urv + (size_t)pt*4608 + px;
  float gU = ur[(0*96 + oc)*16] + uwb[oc];
  float gR = ur[(1*96 + oc)*16] + rwb[oc];
  float gV = ur[(2*96 + oc)*16] + vwb[oc];
  float u = 1.f / (1.f + __expf(-(xU + gU)));
  float r = 1.f / (1.f + __expf(-(xR + gR)));
  float v = xV + r * gV;
  float oi = (v >= 0.f) ? v : 0.2f*v;
  float h0 = hp[(b*96 + oc)*HW + p];
  out[(b*96 + oc)*HW + p] = h0*u + oi*(1.f - u);
}

extern "C" void kernel_launch(void* const* d_in, const int* in_sizes, int n_in,
                              void* d_out, int out_size, void* d_ws, size_t ws_size,
                              hipStream_t stream){
  const float* x    = (const float*)d_in[0];
  const float* hp   = (const float*)d_in[1];
  const float* sw1  = (const float*)d_in[2];
  const float* sb1  = (const float*)d_in[3];
  const float* sw2  = (const float*)d_in[4];
  const float* sb2  = (const float*)d_in[5];
  const float* rw   = (const float*)d_in[6];
  const float* rb   = (const float*)d_in[7];
  const float* uw   = (const float*)d_in[8];
  const float* ub   = (const float*)d_in[9];
  const float* vw   = (const float*)d_in[10];
  const float* vb   = (const float*)d_in[11];
  const float* rww  = (const float*)d_in[12];
  const float* rwb  = (const float*)d_in[13];
  const float* uww  = (const float*)d_in[14];
  const float* uwb  = (const float*)d_in[15];
  const float* vww  = (const float*)d_in[16];
  const float* vwb  = (const float*)d_in[17];

  pack_b_k    <<<dim3((3*96*1248 + 255)/256), dim3(256), 0, stream>>>(uww, rww, vww);
  pack_w1b_k  <<<dim3((25*4*1024 + 255)/256), dim3(256), 0, stream>>>(sw1);
  transpose_k <<<dim3(288, 4, 4), dim3(256), 0, stream>>>(hp, x);
  conv1_mfma_k<<<dim3(144, 1, 4), dim3(512), 0, stream>>>(sb1);
  conv2_k     <<<dim3(36, 4, 4), dim3(256), 0, stream>>>(sw2, sb2);
  gemm_k      <<<dim3(576),      dim3(256), 0, stream>>>();
  gate_k      <<<dim3(36, 96, 4), dim3(256), 0, stream>>>(x, hp,
               uw, ub, rw, rb, vw, vb, uwb, rwb, vwb, (float*)d_out);
}